// Round 6
// baseline (829.361 us; speedup 1.0000x reference)
//
#include <hip/hip_runtime.h>

#define BB   16384
#define NAg  5
#define DD   128
#define HH   128
#define G4   512   // 4*H
#define KC   256   // LS1 + H
#define AA   64
#define CATW 768   // 6*H

typedef __attribute__((ext_vector_type(8))) short bf16x8;
typedef __attribute__((ext_vector_type(4))) float f32x4;

#define DEV static __device__ __forceinline__

DEV unsigned short bf16r(float x){
  unsigned u = __float_as_uint(x);
  unsigned r = (u + 0x7fffu + ((u >> 16) & 1u)) >> 16;
  return (unsigned short)r;
}
DEV float sigf(float x){ return 1.0f / (1.0f + __expf(-x)); }
DEV float tanhf_(float x){ return 2.0f / (1.0f + __expf(-2.0f * x)) - 1.0f; }

DEV bf16x8 ld8(const unsigned short* p){ return *(const bf16x8*)p; }

DEV bf16x8 cvt8(const float* __restrict__ p){
  const float4* q = (const float4*)p;
  float4 v0 = q[0], v1 = q[1];
  bf16x8 r;
  r[0]=(short)bf16r(v0.x); r[1]=(short)bf16r(v0.y); r[2]=(short)bf16r(v0.z); r[3]=(short)bf16r(v0.w);
  r[4]=(short)bf16r(v1.x); r[5]=(short)bf16r(v1.y); r[6]=(short)bf16r(v1.z); r[7]=(short)bf16r(v1.w);
  return r;
}

// ---------------- prep: pack weights to bf16, concat [Wih|Whh], sum biases ---
__global__ void k_prep(const float* __restrict__ d1w, const float* __restrict__ d2w,
                       const float* __restrict__ mWih, const float* __restrict__ mWhh,
                       const float* __restrict__ mbih, const float* __restrict__ mbhh,
                       const float* __restrict__ cWih, const float* __restrict__ cWhh,
                       const float* __restrict__ cbih, const float* __restrict__ cbhh,
                       unsigned short* d1w_bf, unsigned short* d2w_bf,
                       unsigned short* Wm, unsigned short* Wc, float* bm, float* bc)
{
  const long long TOT = 16384 + 49152 + 655360 + 655360 + 2560 + 2560;
  for (long long i = (long long)blockIdx.x * 256 + threadIdx.x; i < TOT;
       i += (long long)gridDim.x * 256) {
    long long x = i;
    if (x < 16384) { d1w_bf[x] = bf16r(d1w[x]); continue; }
    x -= 16384;
    if (x < 49152) { d2w_bf[x] = bf16r(d2w[x]); continue; }
    x -= 49152;
    if (x < 655360) {
      int k = (int)(x & 255); long long gg = x >> 8; // n*512+g
      Wm[x] = bf16r(k < 128 ? mWih[gg * 128 + k] : mWhh[gg * 128 + (k - 128)]);
      continue;
    }
    x -= 655360;
    if (x < 655360) {
      int k = (int)(x & 255); long long gg = x >> 8;
      Wc[x] = bf16r(k < 128 ? cWih[gg * 128 + k] : cWhh[gg * 128 + (k - 128)]);
      continue;
    }
    x -= 655360;
    if (x < 2560) { bm[x] = mbih[x] + mbhh[x]; continue; }
    x -= 2560;
    bc[x] = cbih[x] + cbhh[x];
  }
}

// ---------------- obs = input @ d1_w^T + d1_b   -> bf16 (n,b,128) ------------
__global__ __launch_bounds__(256) void k_obs(const float* __restrict__ input,
                                             const unsigned short* __restrict__ d1w,
                                             const float* __restrict__ d1b,
                                             unsigned short* __restrict__ obs_bf)
{
  const int m0 = blockIdx.x * 64;
  const int w = threadIdx.x >> 6, l = threadIdx.x & 63;
  const int c0l = l & 15, hi = l >> 4;

  const int arow_m = m0 + w * 16 + c0l;           // m = n*B + b
  const int n = arow_m >> 14, b = arow_m & 16383;
  const float* arow = input + ((size_t)b * NAg + n) * DD;

  f32x4 acc[8];
  #pragma unroll
  for (int nt = 0; nt < 8; nt++) acc[nt] = (f32x4){0, 0, 0, 0};

  #pragma unroll
  for (int kt = 0; kt < 4; ++kt) {
    const int k = kt * 32 + hi * 8;
    bf16x8 a = cvt8(arow + k);
    #pragma unroll
    for (int nt = 0; nt < 8; nt++) {
      bf16x8 bfr = ld8(d1w + (size_t)(nt * 16 + c0l) * DD + k);
      acc[nt] = __builtin_amdgcn_mfma_f32_16x16x32_bf16(a, bfr, acc[nt], 0, 0, 0);
    }
  }
  #pragma unroll
  for (int nt = 0; nt < 8; nt++) {
    const int col = nt * 16 + c0l;
    const float bias = d1b[col];
    #pragma unroll
    for (int j = 0; j < 4; j++) {
      const int r = m0 + w * 16 + hi * 4 + j;
      obs_bf[(size_t)r * DD + col] = bf16r(acc[nt][j] + bias);
    }
  }
}

// ---------------- mem LSTM (one step), BM=64: h_n, c_n fp32; mem_h bf16 to cat
__global__ __launch_bounds__(256, 2) void k_mem(const unsigned short* __restrict__ obs_bf,
                                                const float* __restrict__ h0,
                                                const float* __restrict__ c0,
                                                const unsigned short* __restrict__ Wm,
                                                const float* __restrict__ bm,
                                                float* __restrict__ out_h,
                                                float* __restrict__ out_c,
                                                unsigned short* __restrict__ cat)
{
  const int n = blockIdx.x >> 8;            // / 256
  const int b0 = (blockIdx.x & 255) << 6;   // * 64
  const int w = threadIdx.x >> 6, l = threadIdx.x & 63;
  const int c0l = l & 15, hi = l >> 4;

  const unsigned short* Wn = Wm + (size_t)n * G4 * KC;
  f32x4 acc[4][8];
  #pragma unroll
  for (int mt = 0; mt < 4; mt++)
    #pragma unroll
    for (int nt = 0; nt < 8; nt++) acc[mt][nt] = (f32x4){0, 0, 0, 0};

  #pragma unroll
  for (int kt = 0; kt < 8; ++kt) {
    const int k = kt * 32 + hi * 8;
    bf16x8 bfr[8];
    #pragma unroll
    for (int nt = 0; nt < 8; nt++) {
      const int g = (nt >> 1) * 128 + w * 32 + (nt & 1) * 16 + c0l;
      bfr[nt] = ld8(Wn + (size_t)g * KC + k);
    }
    bf16x8 a[4];
    #pragma unroll
    for (int mt = 0; mt < 4; mt++) {
      const int br = b0 + mt * 16 + c0l;
      if (kt < 4) a[mt] = ld8(obs_bf + ((size_t)n * BB + br) * DD + k);
      else        a[mt] = cvt8(h0 + ((size_t)n * BB + br) * HH + (k - 128));
    }
    #pragma unroll
    for (int mt = 0; mt < 4; mt++)
      #pragma unroll
      for (int nt = 0; nt < 8; nt++)
        acc[mt][nt] = __builtin_amdgcn_mfma_f32_16x16x32_bf16(a[mt], bfr[nt], acc[mt][nt], 0, 0, 0);
  }

  #pragma unroll
  for (int uhi = 0; uhi < 2; ++uhi) {
    const int u = w * 32 + uhi * 16 + c0l;
    const float bI = bm[n * G4 + u];
    const float bF = bm[n * G4 + 128 + u];
    const float bG = bm[n * G4 + 256 + u];
    const float bO = bm[n * G4 + 384 + u];
    #pragma unroll
    for (int mt = 0; mt < 4; mt++) {
      #pragma unroll
      for (int j = 0; j < 4; j++) {
        const int br = b0 + mt * 16 + hi * 4 + j;
        const size_t rb = (size_t)n * BB + br;
        const float iv = acc[mt][0 + uhi][j] + bI;
        const float fv = acc[mt][2 + uhi][j] + bF;
        const float gv = acc[mt][4 + uhi][j] + bG;
        const float ov = acc[mt][6 + uhi][j] + bO;
        const float cold = c0[rb * HH + u];
        const float cn = sigf(fv) * cold + sigf(iv) * tanhf_(gv);
        const float hn = sigf(ov) * tanhf_(cn);
        out_h[rb * HH + u] = hn;
        out_c[rb * HH + u] = cn;
        cat[rb * CATW + 640 + u] = bf16r(hn);
      }
    }
  }
}

// ---------------- fused com scan: all 5 steps in one kernel ------------------
// Recurrence is local to (l0, batch-tile): c lives in registers, h crosses
// steps via double-buffered LDS transpose (XOR-swizzled, 2-way max conflict).
__global__ __launch_bounds__(256, 2) void k_comf(const unsigned short* __restrict__ obs_bf,
                                                 const unsigned short* __restrict__ Wc,
                                                 const float* __restrict__ bc,
                                                 unsigned short* __restrict__ cat)
{
  __shared__ __align__(16) unsigned short hl[2][64][128];

  const int l0 = blockIdx.x >> 8;           // / 256
  const int b0 = (blockIdx.x & 255) << 6;   // * 64
  const int w = threadIdx.x >> 6, l = threadIdx.x & 63;
  const int c0l = l & 15, hi = l >> 4;

  const unsigned short* Wn = Wc + (size_t)l0 * G4 * KC;

  // biases hoisted across steps
  float bI[2], bF[2], bG[2], bO[2];
  #pragma unroll
  for (int uhi = 0; uhi < 2; ++uhi) {
    const int u = w * 32 + uhi * 16 + c0l;
    bI[uhi] = bc[l0 * G4 + u];
    bF[uhi] = bc[l0 * G4 + 128 + u];
    bG[uhi] = bc[l0 * G4 + 256 + u];
    bO[uhi] = bc[l0 * G4 + 384 + u];
  }

  float creg[4][2][4];
  #pragma unroll
  for (int mt = 0; mt < 4; mt++)
    #pragma unroll
    for (int uhi = 0; uhi < 2; uhi++)
      #pragma unroll
      for (int j = 0; j < 4; j++) creg[mt][uhi][j] = 0.0f;

  for (int t = 0; t < 5; ++t) {
    const int it = (t == 4) ? l0 : (t + (t >= l0 ? 1 : 0));
    const unsigned short* obsb = obs_bf + (size_t)it * BB * DD;

    f32x4 acc[4][8];
    #pragma unroll
    for (int mt = 0; mt < 4; mt++)
      #pragma unroll
      for (int nt = 0; nt < 8; nt++) acc[mt][nt] = (f32x4){0, 0, 0, 0};

    // K-part 1: x = obs[it]
    #pragma unroll
    for (int kt = 0; kt < 4; ++kt) {
      const int k = kt * 32 + hi * 8;
      bf16x8 bfr[8];
      #pragma unroll
      for (int nt = 0; nt < 8; nt++) {
        const int g = (nt >> 1) * 128 + w * 32 + (nt & 1) * 16 + c0l;
        bfr[nt] = ld8(Wn + (size_t)g * KC + k);
      }
      bf16x8 a[4];
      #pragma unroll
      for (int mt = 0; mt < 4; mt++)
        a[mt] = ld8(obsb + (size_t)(b0 + mt * 16 + c0l) * DD + k);
      #pragma unroll
      for (int mt = 0; mt < 4; mt++)
        #pragma unroll
        for (int nt = 0; nt < 8; nt++)
          acc[mt][nt] = __builtin_amdgcn_mfma_f32_16x16x32_bf16(a[mt], bfr[nt], acc[mt][nt], 0, 0, 0);
    }

    // K-part 2: h from previous step (LDS, swizzled); skipped at t=0 (h=0)
    if (t > 0) {
      const int rbuf = (t - 1) & 1;
      #pragma unroll
      for (int kt = 0; kt < 4; ++kt) {
        const int k = 128 + kt * 32 + hi * 8;
        bf16x8 bfr[8];
        #pragma unroll
        for (int nt = 0; nt < 8; nt++) {
          const int g = (nt >> 1) * 128 + w * 32 + (nt & 1) * 16 + c0l;
          bfr[nt] = ld8(Wn + (size_t)g * KC + k);
        }
        const int u0 = kt * 32 + hi * 8;
        bf16x8 a[4];
        #pragma unroll
        for (int mt = 0; mt < 4; mt++) {
          const int r = mt * 16 + c0l;
          a[mt] = *(const bf16x8*)&hl[rbuf][r][u0 ^ ((r & 7) << 3)];
        }
        #pragma unroll
        for (int mt = 0; mt < 4; mt++)
          #pragma unroll
          for (int nt = 0; nt < 8; nt++)
            acc[mt][nt] = __builtin_amdgcn_mfma_f32_16x16x32_bf16(a[mt], bfr[nt], acc[mt][nt], 0, 0, 0);
      }
    }

    // epilogue: LSTM nonlinearity; h -> LDS (next buf) + global cat
    const int wbuf = t & 1;
    #pragma unroll
    for (int uhi = 0; uhi < 2; ++uhi) {
      const int us = w * 32 + uhi * 16 + c0l;
      #pragma unroll
      for (int mt = 0; mt < 4; mt++) {
        #pragma unroll
        for (int j = 0; j < 4; j++) {
          const int r = mt * 16 + hi * 4 + j;
          const int br = b0 + r;
          const float iv = acc[mt][0 + uhi][j] + bI[uhi];
          const float fv = acc[mt][2 + uhi][j] + bF[uhi];
          const float gv = acc[mt][4 + uhi][j] + bG[uhi];
          const float ov = acc[mt][6 + uhi][j] + bO[uhi];
          const float cn = sigf(fv) * creg[mt][uhi][j] + sigf(iv) * tanhf_(gv);
          const float hn = sigf(ov) * tanhf_(cn);
          creg[mt][uhi][j] = cn;
          const unsigned short hb = bf16r(hn);
          hl[wbuf][r][us ^ ((r & 7) << 3)] = hb;
          cat[((size_t)it * BB + br) * CATW + l0 * 128 + us] = hb;
        }
      }
    }
    __syncthreads();
  }
}

// ---------------- outs = cat @ d2_w^T + d2_b  -> d_out[0 .. 5*B*64) ----------
__global__ __launch_bounds__(256) void k_d2(const unsigned short* __restrict__ cat,
                                            const unsigned short* __restrict__ d2w,
                                            const float* __restrict__ d2b,
                                            float* __restrict__ out)
{
  const int m0 = blockIdx.x * 64;
  const int w = threadIdx.x >> 6, l = threadIdx.x & 63;
  const int c0l = l & 15, hi = l >> 4;

  const unsigned short* arow = cat + (size_t)(m0 + w * 16 + c0l) * CATW;
  f32x4 acc[4];
  #pragma unroll
  for (int nt = 0; nt < 4; nt++) acc[nt] = (f32x4){0, 0, 0, 0};

  #pragma unroll 4
  for (int kt = 0; kt < 24; ++kt) {
    const int k = kt * 32 + hi * 8;
    bf16x8 a = ld8(arow + k);
    #pragma unroll
    for (int nt = 0; nt < 4; nt++) {
      bf16x8 bfr = ld8(d2w + (size_t)(nt * 16 + c0l) * CATW + k);
      acc[nt] = __builtin_amdgcn_mfma_f32_16x16x32_bf16(a, bfr, acc[nt], 0, 0, 0);
    }
  }
  #pragma unroll
  for (int nt = 0; nt < 4; nt++) {
    const int col = nt * 16 + c0l;
    const float bias = d2b[col];
    #pragma unroll
    for (int j = 0; j < 4; j++) {
      const int r = m0 + w * 16 + hi * 4 + j;
      out[(size_t)r * AA + col] = acc[nt][j] + bias;
    }
  }
}

extern "C" void kernel_launch(void* const* d_in, const int* in_sizes, int n_in,
                              void* d_out, int out_size, void* d_ws, size_t ws_size,
                              hipStream_t stream)
{
  const float* input = (const float*)d_in[0];
  const float* h0    = (const float*)d_in[1];
  const float* c0    = (const float*)d_in[2];
  const float* d1w   = (const float*)d_in[3];
  const float* d1b   = (const float*)d_in[4];
  const float* d2w   = (const float*)d_in[5];
  const float* d2b   = (const float*)d_in[6];
  const float* mWih  = (const float*)d_in[7];
  const float* mWhh  = (const float*)d_in[8];
  const float* mbih  = (const float*)d_in[9];
  const float* mbhh  = (const float*)d_in[10];
  const float* cWih  = (const float*)d_in[11];
  const float* cWhh  = (const float*)d_in[12];
  const float* cbih  = (const float*)d_in[13];
  const float* cbhh  = (const float*)d_in[14];
  float* out = (float*)d_out;

  char* ws = (char*)d_ws;
  size_t off = 0;
  auto alloc = [&](size_t bytes) { void* p = ws + off; off += (bytes + 255) & ~255ull; return p; };
  unsigned short* d1w_bf = (unsigned short*)alloc(16384 * 2);
  unsigned short* d2w_bf = (unsigned short*)alloc(49152 * 2);
  unsigned short* Wm     = (unsigned short*)alloc(655360 * 2);
  unsigned short* Wcb    = (unsigned short*)alloc(655360 * 2);
  float* bm              = (float*)alloc(2560 * 4);
  float* bc              = (float*)alloc(2560 * 4);
  unsigned short* obs_bf = (unsigned short*)alloc((size_t)NAg * BB * DD * 2);
  unsigned short* cat    = (unsigned short*)alloc((size_t)NAg * BB * CATW * 2);

  float* out_h = out + (size_t)NAg * BB * AA;
  float* out_c = out_h + (size_t)NAg * BB * HH;

  k_prep<<<2048, 256, 0, stream>>>(d1w, d2w, mWih, mWhh, mbih, mbhh,
                                   cWih, cWhh, cbih, cbhh,
                                   d1w_bf, d2w_bf, Wm, Wcb, bm, bc);
  k_obs<<<(NAg * BB) / 64, 256, 0, stream>>>(input, d1w_bf, d1b, obs_bf);
  k_mem<<<(NAg * BB) / 64, 256, 0, stream>>>(obs_bf, h0, c0, Wm, bm, out_h, out_c, cat);
  k_comf<<<(NAg * BB) / 64, 256, 0, stream>>>(obs_bf, Wcb, bc, cat);
  k_d2<<<(NAg * BB) / 64, 256, 0, stream>>>(cat, d2w_bf, d2b, out);
}

// Round 7
// 735.011 us; speedup vs baseline: 1.1284x; 1.1284x over previous
//
#include <hip/hip_runtime.h>

#define BB   16384
#define NAg  5
#define DD   128
#define HH   128
#define G4   512   // 4*H
#define KC   256   // LS1 + H
#define AA   64
#define CATW 768   // 6*H

typedef __attribute__((ext_vector_type(8))) short bf16x8;
typedef __attribute__((ext_vector_type(4))) float f32x4;

#define DEV static __device__ __forceinline__

DEV unsigned short bf16r(float x){
  unsigned u = __float_as_uint(x);
  unsigned r = (u + 0x7fffu + ((u >> 16) & 1u)) >> 16;
  return (unsigned short)r;
}
DEV float sigf(float x){ return 1.0f / (1.0f + __expf(-x)); }
DEV float tanhf_(float x){ return 2.0f / (1.0f + __expf(-2.0f * x)) - 1.0f; }

DEV bf16x8 ld8(const unsigned short* p){ return *(const bf16x8*)p; }

DEV bf16x8 cvt8(const float* __restrict__ p){
  const float4* q = (const float4*)p;
  float4 v0 = q[0], v1 = q[1];
  bf16x8 r;
  r[0]=(short)bf16r(v0.x); r[1]=(short)bf16r(v0.y); r[2]=(short)bf16r(v0.z); r[3]=(short)bf16r(v0.w);
  r[4]=(short)bf16r(v1.x); r[5]=(short)bf16r(v1.y); r[6]=(short)bf16r(v1.z); r[7]=(short)bf16r(v1.w);
  return r;
}

// ---------------- prep: pack weights to bf16, concat [Wih|Whh], sum biases ---
__global__ void k_prep(const float* __restrict__ d1w, const float* __restrict__ d2w,
                       const float* __restrict__ mWih, const float* __restrict__ mWhh,
                       const float* __restrict__ mbih, const float* __restrict__ mbhh,
                       const float* __restrict__ cWih, const float* __restrict__ cWhh,
                       const float* __restrict__ cbih, const float* __restrict__ cbhh,
                       unsigned short* d1w_bf, unsigned short* d2w_bf,
                       unsigned short* Wm, unsigned short* Wc, float* bm, float* bc)
{
  const long long TOT = 16384 + 49152 + 655360 + 655360 + 2560 + 2560;
  for (long long i = (long long)blockIdx.x * 256 + threadIdx.x; i < TOT;
       i += (long long)gridDim.x * 256) {
    long long x = i;
    if (x < 16384) { d1w_bf[x] = bf16r(d1w[x]); continue; }
    x -= 16384;
    if (x < 49152) { d2w_bf[x] = bf16r(d2w[x]); continue; }
    x -= 49152;
    if (x < 655360) {
      int k = (int)(x & 255); long long gg = x >> 8; // n*512+g
      Wm[x] = bf16r(k < 128 ? mWih[gg * 128 + k] : mWhh[gg * 128 + (k - 128)]);
      continue;
    }
    x -= 655360;
    if (x < 655360) {
      int k = (int)(x & 255); long long gg = x >> 8;
      Wc[x] = bf16r(k < 128 ? cWih[gg * 128 + k] : cWhh[gg * 128 + (k - 128)]);
      continue;
    }
    x -= 655360;
    if (x < 2560) { bm[x] = mbih[x] + mbhh[x]; continue; }
    x -= 2560;
    bc[x] = cbih[x] + cbhh[x];
  }
}

// ---------------- obs = input @ d1_w^T + d1_b -> bf16 (n,b,128), staged ------
__global__ __launch_bounds__(256) void k_obs(const float* __restrict__ input,
                                             const unsigned short* __restrict__ d1w,
                                             const float* __restrict__ d1b,
                                             unsigned short* __restrict__ obs_bf)
{
  __shared__ __align__(16) unsigned short ob[64][128];

  const int m0 = blockIdx.x * 64;
  const int w = threadIdx.x >> 6, l = threadIdx.x & 63;
  const int c0l = l & 15, hi = l >> 4;

  const int arow_m = m0 + w * 16 + c0l;           // m = n*B + b
  const int n = arow_m >> 14, b = arow_m & 16383;
  const float* arow = input + ((size_t)b * NAg + n) * DD;

  f32x4 acc[8];
  #pragma unroll
  for (int nt = 0; nt < 8; nt++) acc[nt] = (f32x4){0, 0, 0, 0};

  #pragma unroll
  for (int kt = 0; kt < 4; ++kt) {
    const int k = kt * 32 + hi * 8;
    bf16x8 a = cvt8(arow + k);
    #pragma unroll
    for (int nt = 0; nt < 8; nt++) {
      bf16x8 bfr = ld8(d1w + (size_t)(nt * 16 + c0l) * DD + k);
      acc[nt] = __builtin_amdgcn_mfma_f32_16x16x32_bf16(a, bfr, acc[nt], 0, 0, 0);
    }
  }
  #pragma unroll
  for (int nt = 0; nt < 8; nt++) {
    const int col = nt * 16 + c0l;
    const float bias = d1b[col];
    #pragma unroll
    for (int j = 0; j < 4; j++) {
      const int lr = w * 16 + hi * 4 + j;
      ob[lr][col ^ ((lr & 7) << 3)] = bf16r(acc[nt][j] + bias);
    }
  }
  __syncthreads();
  // coalesced wide copy LDS -> global (128B lines per 16-lane group)
  #pragma unroll
  for (int cc = 0; cc < 4; ++cc) {
    const int idx = cc * 256 + threadIdx.x;   // 16B chunk id
    const int r = idx >> 4;
    const int c8 = (idx & 15) << 3;
    const int cs = c8 ^ ((r & 7) << 3);
    bf16x8 v = *(const bf16x8*)&ob[r][cs];
    *(bf16x8*)(obs_bf + (size_t)(m0 + r) * DD + c8) = v;
  }
}

// ---------------- mem LSTM (one step), BM=64; cat slice staged in LDS --------
__global__ __launch_bounds__(256, 2) void k_mem(const unsigned short* __restrict__ obs_bf,
                                                const float* __restrict__ h0,
                                                const float* __restrict__ c0,
                                                const unsigned short* __restrict__ Wm,
                                                const float* __restrict__ bm,
                                                float* __restrict__ out_h,
                                                float* __restrict__ out_c,
                                                unsigned short* __restrict__ cat)
{
  __shared__ __align__(16) unsigned short hm[64][128];

  const int n = blockIdx.x >> 8;            // / 256
  const int b0 = (blockIdx.x & 255) << 6;   // * 64
  const int w = threadIdx.x >> 6, l = threadIdx.x & 63;
  const int c0l = l & 15, hi = l >> 4;

  const unsigned short* Wn = Wm + (size_t)n * G4 * KC;
  f32x4 acc[4][8];
  #pragma unroll
  for (int mt = 0; mt < 4; mt++)
    #pragma unroll
    for (int nt = 0; nt < 8; nt++) acc[mt][nt] = (f32x4){0, 0, 0, 0};

  #pragma unroll
  for (int kt = 0; kt < 8; ++kt) {
    const int k = kt * 32 + hi * 8;
    bf16x8 bfr[8];
    #pragma unroll
    for (int nt = 0; nt < 8; nt++) {
      const int g = (nt >> 1) * 128 + w * 32 + (nt & 1) * 16 + c0l;
      bfr[nt] = ld8(Wn + (size_t)g * KC + k);
    }
    bf16x8 a[4];
    #pragma unroll
    for (int mt = 0; mt < 4; mt++) {
      const int br = b0 + mt * 16 + c0l;
      if (kt < 4) a[mt] = ld8(obs_bf + ((size_t)n * BB + br) * DD + k);
      else        a[mt] = cvt8(h0 + ((size_t)n * BB + br) * HH + (k - 128));
    }
    #pragma unroll
    for (int mt = 0; mt < 4; mt++)
      #pragma unroll
      for (int nt = 0; nt < 8; nt++)
        acc[mt][nt] = __builtin_amdgcn_mfma_f32_16x16x32_bf16(a[mt], bfr[nt], acc[mt][nt], 0, 0, 0);
  }

  #pragma unroll
  for (int uhi = 0; uhi < 2; ++uhi) {
    const int u = w * 32 + uhi * 16 + c0l;
    const float bI = bm[n * G4 + u];
    const float bF = bm[n * G4 + 128 + u];
    const float bG = bm[n * G4 + 256 + u];
    const float bO = bm[n * G4 + 384 + u];
    #pragma unroll
    for (int mt = 0; mt < 4; mt++) {
      #pragma unroll
      for (int j = 0; j < 4; j++) {
        const int r = mt * 16 + hi * 4 + j;
        const size_t rb = (size_t)n * BB + b0 + r;
        const float iv = acc[mt][0 + uhi][j] + bI;
        const float fv = acc[mt][2 + uhi][j] + bF;
        const float gv = acc[mt][4 + uhi][j] + bG;
        const float ov = acc[mt][6 + uhi][j] + bO;
        const float cold = c0[rb * HH + u];
        const float cn = sigf(fv) * cold + sigf(iv) * tanhf_(gv);
        const float hn = sigf(ov) * tanhf_(cn);
        out_h[rb * HH + u] = hn;
        out_c[rb * HH + u] = cn;
        hm[r][u ^ ((r & 7) << 3)] = bf16r(hn);
      }
    }
  }
  __syncthreads();
  #pragma unroll
  for (int cc = 0; cc < 4; ++cc) {
    const int idx = cc * 256 + threadIdx.x;
    const int r = idx >> 4;
    const int c8 = (idx & 15) << 3;
    const int cs = c8 ^ ((r & 7) << 3);
    bf16x8 v = *(const bf16x8*)&hm[r][cs];
    *(bf16x8*)(cat + ((size_t)n * BB + b0 + r) * CATW + 640 + c8) = v;
  }
}

// ---------------- fused com scan: all 5 steps in one kernel ------------------
// c in registers; h crosses steps via double-buffered swizzled LDS; cat is
// written via coalesced wide copy from the same LDS buffer.
__global__ __launch_bounds__(256, 2) void k_comf(const unsigned short* __restrict__ obs_bf,
                                                 const unsigned short* __restrict__ Wc,
                                                 const float* __restrict__ bc,
                                                 unsigned short* __restrict__ cat)
{
  __shared__ __align__(16) unsigned short hl[2][64][128];

  const int l0 = blockIdx.x >> 8;           // / 256
  const int b0 = (blockIdx.x & 255) << 6;   // * 64
  const int w = threadIdx.x >> 6, l = threadIdx.x & 63;
  const int c0l = l & 15, hi = l >> 4;

  const unsigned short* Wn = Wc + (size_t)l0 * G4 * KC;

  float bI[2], bF[2], bG[2], bO[2];
  #pragma unroll
  for (int uhi = 0; uhi < 2; ++uhi) {
    const int u = w * 32 + uhi * 16 + c0l;
    bI[uhi] = bc[l0 * G4 + u];
    bF[uhi] = bc[l0 * G4 + 128 + u];
    bG[uhi] = bc[l0 * G4 + 256 + u];
    bO[uhi] = bc[l0 * G4 + 384 + u];
  }

  float creg[4][2][4];
  #pragma unroll
  for (int mt = 0; mt < 4; mt++)
    #pragma unroll
    for (int uhi = 0; uhi < 2; uhi++)
      #pragma unroll
      for (int j = 0; j < 4; j++) creg[mt][uhi][j] = 0.0f;

  for (int t = 0; t < 5; ++t) {
    const int it = (t == 4) ? l0 : (t + (t >= l0 ? 1 : 0));
    const unsigned short* obsb = obs_bf + (size_t)it * BB * DD;

    f32x4 acc[4][8];
    #pragma unroll
    for (int mt = 0; mt < 4; mt++)
      #pragma unroll
      for (int nt = 0; nt < 8; nt++) acc[mt][nt] = (f32x4){0, 0, 0, 0};

    // K-part 1: x = obs[it]
    #pragma unroll
    for (int kt = 0; kt < 4; ++kt) {
      const int k = kt * 32 + hi * 8;
      bf16x8 bfr[8];
      #pragma unroll
      for (int nt = 0; nt < 8; nt++) {
        const int g = (nt >> 1) * 128 + w * 32 + (nt & 1) * 16 + c0l;
        bfr[nt] = ld8(Wn + (size_t)g * KC + k);
      }
      bf16x8 a[4];
      #pragma unroll
      for (int mt = 0; mt < 4; mt++)
        a[mt] = ld8(obsb + (size_t)(b0 + mt * 16 + c0l) * DD + k);
      #pragma unroll
      for (int mt = 0; mt < 4; mt++)
        #pragma unroll
        for (int nt = 0; nt < 8; nt++)
          acc[mt][nt] = __builtin_amdgcn_mfma_f32_16x16x32_bf16(a[mt], bfr[nt], acc[mt][nt], 0, 0, 0);
    }

    // K-part 2: h from previous step (LDS, swizzled); skipped at t=0 (h=0)
    if (t > 0) {
      const int rbuf = (t - 1) & 1;
      #pragma unroll
      for (int kt = 0; kt < 4; ++kt) {
        const int k = 128 + kt * 32 + hi * 8;
        bf16x8 bfr[8];
        #pragma unroll
        for (int nt = 0; nt < 8; nt++) {
          const int g = (nt >> 1) * 128 + w * 32 + (nt & 1) * 16 + c0l;
          bfr[nt] = ld8(Wn + (size_t)g * KC + k);
        }
        const int u0 = kt * 32 + hi * 8;
        bf16x8 a[4];
        #pragma unroll
        for (int mt = 0; mt < 4; mt++) {
          const int r = mt * 16 + c0l;
          a[mt] = *(const bf16x8*)&hl[rbuf][r][u0 ^ ((r & 7) << 3)];
        }
        #pragma unroll
        for (int mt = 0; mt < 4; mt++)
          #pragma unroll
          for (int nt = 0; nt < 8; nt++)
            acc[mt][nt] = __builtin_amdgcn_mfma_f32_16x16x32_bf16(a[mt], bfr[nt], acc[mt][nt], 0, 0, 0);
      }
    }

    // epilogue: LSTM nonlinearity; h -> LDS only
    const int wbuf = t & 1;
    #pragma unroll
    for (int uhi = 0; uhi < 2; ++uhi) {
      const int us = w * 32 + uhi * 16 + c0l;
      #pragma unroll
      for (int mt = 0; mt < 4; mt++) {
        #pragma unroll
        for (int j = 0; j < 4; j++) {
          const int r = mt * 16 + hi * 4 + j;
          const float iv = acc[mt][0 + uhi][j] + bI[uhi];
          const float fv = acc[mt][2 + uhi][j] + bF[uhi];
          const float gv = acc[mt][4 + uhi][j] + bG[uhi];
          const float ov = acc[mt][6 + uhi][j] + bO[uhi];
          const float cn = sigf(fv) * creg[mt][uhi][j] + sigf(iv) * tanhf_(gv);
          const float hn = sigf(ov) * tanhf_(cn);
          creg[mt][uhi][j] = cn;
          hl[wbuf][r][us ^ ((r & 7) << 3)] = bf16r(hn);
        }
      }
    }
    __syncthreads();

    // coalesced wide copy hl[wbuf] -> cat (full 128B lines)
    unsigned short* catb = cat + ((size_t)it * BB + b0) * CATW + l0 * 128;
    #pragma unroll
    for (int cc = 0; cc < 4; ++cc) {
      const int idx = cc * 256 + threadIdx.x;
      const int r = idx >> 4;
      const int c8 = (idx & 15) << 3;
      const int cs = c8 ^ ((r & 7) << 3);
      bf16x8 v = *(const bf16x8*)&hl[wbuf][r][cs];
      *(bf16x8*)(catb + (size_t)r * CATW + c8) = v;
    }
  }
}

// ---------------- outs = cat @ d2_w^T + d2_b  -> d_out[0 .. 5*B*64) ----------
__global__ __launch_bounds__(256) void k_d2(const unsigned short* __restrict__ cat,
                                            const unsigned short* __restrict__ d2w,
                                            const float* __restrict__ d2b,
                                            float* __restrict__ out)
{
  const int m0 = blockIdx.x * 64;
  const int w = threadIdx.x >> 6, l = threadIdx.x & 63;
  const int c0l = l & 15, hi = l >> 4;

  const unsigned short* arow = cat + (size_t)(m0 + w * 16 + c0l) * CATW;
  f32x4 acc[4];
  #pragma unroll
  for (int nt = 0; nt < 4; nt++) acc[nt] = (f32x4){0, 0, 0, 0};

  #pragma unroll 4
  for (int kt = 0; kt < 24; ++kt) {
    const int k = kt * 32 + hi * 8;
    bf16x8 a = ld8(arow + k);
    #pragma unroll
    for (int nt = 0; nt < 4; nt++) {
      bf16x8 bfr = ld8(d2w + (size_t)(nt * 16 + c0l) * CATW + k);
      acc[nt] = __builtin_amdgcn_mfma_f32_16x16x32_bf16(a, bfr, acc[nt], 0, 0, 0);
    }
  }
  #pragma unroll
  for (int nt = 0; nt < 4; nt++) {
    const int col = nt * 16 + c0l;
    const float bias = d2b[col];
    #pragma unroll
    for (int j = 0; j < 4; j++) {
      const int r = m0 + w * 16 + hi * 4 + j;
      out[(size_t)r * AA + col] = acc[nt][j] + bias;
    }
  }
}

extern "C" void kernel_launch(void* const* d_in, const int* in_sizes, int n_in,
                              void* d_out, int out_size, void* d_ws, size_t ws_size,
                              hipStream_t stream)
{
  const float* input = (const float*)d_in[0];
  const float* h0    = (const float*)d_in[1];
  const float* c0    = (const float*)d_in[2];
  const float* d1w   = (const float*)d_in[3];
  const float* d1b   = (const float*)d_in[4];
  const float* d2w   = (const float*)d_in[5];
  const float* d2b   = (const float*)d_in[6];
  const float* mWih  = (const float*)d_in[7];
  const float* mWhh  = (const float*)d_in[8];
  const float* mbih  = (const float*)d_in[9];
  const float* mbhh  = (const float*)d_in[10];
  const float* cWih  = (const float*)d_in[11];
  const float* cWhh  = (const float*)d_in[12];
  const float* cbih  = (const float*)d_in[13];
  const float* cbhh  = (const float*)d_in[14];
  float* out = (float*)d_out;

  char* ws = (char*)d_ws;
  size_t off = 0;
  auto alloc = [&](size_t bytes) { void* p = ws + off; off += (bytes + 255) & ~255ull; return p; };
  unsigned short* d1w_bf = (unsigned short*)alloc(16384 * 2);
  unsigned short* d2w_bf = (unsigned short*)alloc(49152 * 2);
  unsigned short* Wm     = (unsigned short*)alloc(655360 * 2);
  unsigned short* Wcb    = (unsigned short*)alloc(655360 * 2);
  float* bm              = (float*)alloc(2560 * 4);
  float* bc              = (float*)alloc(2560 * 4);
  unsigned short* obs_bf = (unsigned short*)alloc((size_t)NAg * BB * DD * 2);
  unsigned short* cat    = (unsigned short*)alloc((size_t)NAg * BB * CATW * 2);

  float* out_h = out + (size_t)NAg * BB * AA;
  float* out_c = out_h + (size_t)NAg * BB * HH;

  k_prep<<<2048, 256, 0, stream>>>(d1w, d2w, mWih, mWhh, mbih, mbhh,
                                   cWih, cWhh, cbih, cbhh,
                                   d1w_bf, d2w_bf, Wm, Wcb, bm, bc);
  k_obs<<<(NAg * BB) / 64, 256, 0, stream>>>(input, d1w_bf, d1b, obs_bf);
  k_mem<<<(NAg * BB) / 64, 256, 0, stream>>>(obs_bf, h0, c0, Wm, bm, out_h, out_c, cat);
  k_comf<<<(NAg * BB) / 64, 256, 0, stream>>>(obs_bf, Wcb, bc, cat);
  k_d2<<<(NAg * BB) / 64, 256, 0, stream>>>(cat, d2w_bf, d2b, out);
}